// Round 15
// baseline (543.616 us; speedup 1.0000x reference)
//
#include <hip/hip_runtime.h>
#include <math.h>

// RealNVP, 8 layers, B=262144, H=128. Multi-kernel, 3 dispatches/layer.
// k_bin: 512 blocks x 512 threads (2 blocks/CU -> barrier/atomic-tail
//   stalls of one block overlap with the other block's waves). 4 chunks
//   of 32 sorted units; toggle d1 register-cached (rT1_[32], static
//   unroll); d0 = -d1*ts. float4-packed LDS traffic. Lane-slotted hist.
// k_prep2: per-bin segment tables U/UP/C.
// k_step: 2-round search + 1 float4 + 2 fma + coupling; packed float4 state.
// Global atomics 64-WAY slotted (confirmed mechanism r14: 8->32 gave -25us).

#define BN_ 262144
#define H_ 128
#define NBINS 129

// ws element offsets (4B units)
#define OFF_STAT 0                       // [l][64 slots][2] = 1024
#define OFF_PM   1024                    // [l][64 slots][256] -> 132096
#define OFF_TS   132096                  // 128 -> 132224
#define OFF_XQ   132224                  // float4 xq[BN] -> 1180800
#define OFF_KB   1180800                 // uchar[BN] -> 1246336
#define OFF_V2T  1246336                 // v2T[8][128][128] -> 1377408
#define OFF_WSC  1377408                 // [8][128] -> 1378432
#define OFF_S    1378432                 // float2 ST[129][128] -> 1411456
#define OFF_UP   1411456                 // Upiv[129][8] (16B aligned) -> 1412488
#define OFF_U    1412488                 // U[129][128] (16B aligned) -> 1429000
#define OFF_C    1429000                 // float4 C[129][132] (16B aligned)

__device__ __forceinline__ float4 bsum4(float4 v, volatile float* tmp, int tid) {
    for (int off = 32; off; off >>= 1) {
        v.x += __shfl_down(v.x, off); v.y += __shfl_down(v.y, off);
        v.z += __shfl_down(v.z, off); v.w += __shfl_down(v.w, off);
    }
    if ((tid & 63) == 0) {
        int w = (tid >> 6) * 4;
        tmp[w] = v.x; tmp[w+1] = v.y; tmp[w+2] = v.z; tmp[w+3] = v.w;
    }
    __syncthreads();
    float4 r = make_float4(tmp[0]+tmp[4], tmp[1]+tmp[5],
                           tmp[2]+tmp[6], tmp[3]+tmp[7]);
    __syncthreads();
    return r;
}

// 256x1024: stats of x1 (layer-0 xin, 64-slotted) + v2 transpose + wsc.
__global__ __launch_bounds__(1024) void k_init(const float* __restrict__ x,
    const float* __restrict__ v2, const float* __restrict__ g2,
    float* __restrict__ ws) {
    const int tid = threadIdx.x;
    __shared__ float rs[16], rss[16], w2[16];
    int b = blockIdx.x * 1024 + tid;
    float2 xv = ((const float2*)x)[b];
    float s1 = xv.y, s2 = xv.y * xv.y;
    for (int off = 32; off; off >>= 1) {
        s1 += __shfl_down(s1, off); s2 += __shfl_down(s2, off);
    }
    if ((tid & 63) == 0) { rs[tid>>6] = s1; rss[tid>>6] = s2; }
    __syncthreads();
    if (tid == 0) {
        float a = 0.f, c = 0.f;
        for (int w = 0; w < 16; w++) { a += rs[w]; c += rss[w]; }
        atomicAdd(&ws[OFF_STAT + (blockIdx.x & 63)*2], a);
        atomicAdd(&ws[OFF_STAT + (blockIdx.x & 63)*2 + 1], c);
    }
    if (blockIdx.x < 128) {
        const int l = blockIdx.x >> 4, i0 = (blockIdx.x & 15) * 8;
        const int iloc = tid >> 7, j = tid & 127;
        float val = v2[(l*H_ + i0 + iloc)*H_ + j];
        ws[OFF_V2T + (l*H_ + j)*H_ + i0 + iloc] = val;
        float s = val * val;
        for (int off = 32; off; off >>= 1) s += __shfl_down(s, off);
        if ((tid & 63) == 0) w2[tid >> 6] = s;
        __syncthreads();
        if (tid < 8)
            ws[OFF_WSC + l*H_ + i0 + tid] =
                g2[l*H_ + i0 + tid] / sqrtf(w2[2*tid] + w2[2*tid+1]);
    }
}

// 512 blocks x 512 threads: BN1 fold + rank + binning + hist + moment fold.
// 2 blocks/CU: barrier and atomic-tail stalls overlap across blocks.
__global__ __launch_bounds__(512, 4) void k_bin(
    const float* __restrict__ x,
    const float* __restrict__ v1, const float* __restrict__ g1,
    const float* __restrict__ bn1g, const float* __restrict__ bn1b,
    const float* __restrict__ b2,
    float* __restrict__ ws, int l, int rev) {
    __shared__ float sTun[H_], sTs[H_], wscs[H_], b2s[H_];
    __shared__ float4 tcoef[H_];      // (ta, tc, ba, bc) sorted order
    __shared__ int ordr[H_];
    __shared__ float4 pTB[4][H_];     // (t1, t0, b1, b0)
    __shared__ float scratch[4192];   // ph1: prank[0,512) | ph3.5+: hist4[0,528)
                                      // ph2-3.5: lb[1024,4192) | end: red2[1024,2048)
    float* lb = scratch + 1024;
    float4* hist4 = (float4*)scratch;
    const int tid = threadIdx.x;
    const int i = tid & 127, cc = tid >> 7;   // cc in [0,4)
    const float* v2T = ws + OFF_V2T + l*H_*H_;
    const int b = blockIdx.x * 512 + tid;

    float xin;                        // early issue: hides HBM latency
    if (l == 0) xin = ((const float2*)x)[b].y;
    else {
        float4 xq = ((const float4*)(ws + OFF_XQ))[b];
        xin = rev ? xq.y : xq.x;
    }

    float a = 0.f, c = 0.f, tj = 0.f;
    if (tid < H_) {                   // phase 0: BN1 fold (block-redundant)
        float Ssum = 0.f, SSq = 0.f;
        #pragma unroll
        for (int s = 0; s < 64; ++s) {
            Ssum += ws[OFF_STAT + l*128 + 2*s];
            SSq  += ws[OFF_STAT + l*128 + 2*s + 1];
        }
        float mx = Ssum * (1.f / BN_);
        float vx = fmaxf(SSq * (1.f / BN_) - mx * mx, 0.f);
        float g1v = g1[l*H_ + tid];
        float w1 = (v1[l*H_ + tid] >= 0.f) ? g1v : -g1v;
        float r = rsqrtf(vx * g1v * g1v + 1e-5f);
        a = w1 * r * bn1g[l*H_ + tid];
        c = bn1b[l*H_ + tid] - mx * a;
        tj = (a != 0.f) ? (-c / a) : 3.0e38f;
        sTun[tid] = tj;
        wscs[tid] = ws[OFF_WSC + l*H_ + tid];
        b2s[tid] = b2[l*H_ + tid];
    }
    for (int e = tid; e < 3168; e += 512) lb[e] = 0.f;
    __syncthreads();
    {                                 // phase 1: rank (4 partial segments)
        int* prank = (int*)scratch;
        float tq0 = sTun[i];
        int pr = 0;
        #pragma unroll
        for (int m = 0; m < 32; ++m) {
            int q = cc*32 + m;
            float tq = sTun[q];
            pr += (tq < tq0 || (tq == tq0 && q < i)) ? 1 : 0;
        }
        prank[cc*128 + i] = pr;
        __syncthreads();
        if (tid < H_) {
            int rk = 0;
            #pragma unroll
            for (int s = 0; s < 4; ++s) rk += prank[s*128 + tid];
            ordr[rk] = tid;
            sTs[rk] = tj;
            if (blockIdx.x == 0) ws[OFF_TS + rk] = tj;
            float sg = (a > 0.f) ? 1.f : -1.f;
            bool nz = (a != 0.f);
            bool act = (a < 0.f) || (a == 0.f && c > 0.f);
            tcoef[rk] = make_float4(nz ? sg * a : 0.f, nz ? sg * c : 0.f,
                                    act ? a : 0.f,     act ? c : 0.f);
        }
    }
    __syncthreads();
    float rT1_[32];
    {                                 // phase 2+3: bin/hist + sorted fma pass
        int pos = 0;
        #pragma unroll
        for (int s = 64; s; s >>= 1) pos += (sTs[pos + s - 1] < xin) ? s : 0;
        pos += (sTs[pos] < xin) ? 1 : 0;
        ((unsigned char*)(ws + OFF_KB))[b] = (unsigned char)pos;
        float* lbr = lb + (tid & 7) * 396;   // lane slotting: <=8-way RMW
        atomicAdd(&lbr[pos], 1.f);
        atomicAdd(&lbr[132 + pos], xin);
        atomicAdd(&lbr[264 + pos], xin * xin);

        float b1 = 0.f, b0 = 0.f, t1 = 0.f, t0 = 0.f;
        #pragma unroll
        for (int m = 0; m < 32; ++m) {
            int sm = cc*32 + m;
            float4 t4 = tcoef[sm];                // 1 b128 broadcast
            float vm = v2T[ordr[sm]*H_ + i];      // 1 b32 bcast + L2
            b1 = fmaf(vm, t4.z, b1);
            b0 = fmaf(vm, t4.w, b0);
            float d1 = vm * t4.x;
            t0 = fmaf(vm, t4.y, t0);
            rT1_[m] = d1; t1 += d1;
        }
        pTB[cc][i] = make_float4(t1, t0, b1, b0); // 1 b128 write
    }
    __syncthreads();
    // phase 3.5: merge 8 sub-histogram slots -> packed hist4 (cn, sx, sxx)
    if (tid < 132) {
        float cn = 0.f, sx = 0.f, sxx = 0.f;
        #pragma unroll
        for (int c2 = 0; c2 < 8; ++c2) {
            cn  += lb[c2*396 + tid];
            sx  += lb[c2*396 + 132 + tid];
            sxx += lb[c2*396 + 264 + tid];
        }
        hist4[tid] = make_float4(cn, sx, sxx, 0.f);
    }
    __syncthreads();
    {                                 // phase 4: prefix walk (registers) + fold
        float S1 = 0.f, S0 = 0.f;
        #pragma unroll
        for (int c2 = 0; c2 < 4; ++c2) {
            float4 p = pTB[c2][i];                // 1 b128 read
            S1 += p.z; S0 += p.w;
            if (c2 < cc) { S1 += p.x; S0 += p.y; }
        }
        float wsci = wscs[i], b2i = b2s[i];
        float pm = 0.f, pe = 0.f;
        float2* STg = (float2*)(ws + OFF_S);
        #pragma unroll
        for (int r = 0; r < 32; ++r) {
            int k = 32*cc + r;
            float4 h = hist4[k];                  // 1 b128 broadcast
            float A = wsci * S1;
            float B = fmaf(wsci, S0, b2i);
            if (blockIdx.x == 0) STg[k*H_ + i] = make_float2(A, B);
            pm += A*h.y + B*h.x;
            pe += A*A*h.z + 2.f*A*B*h.y + B*B*h.x;
            float d1 = rT1_[r];
            S1 += d1;
            S0 = fmaf(-d1, sTs[k], S0);           // d0 = -d1*ts (exact algebra)
        }
        if (cc == 3) {                // bin 128 (no toggle after)
            float4 h = hist4[128];
            float A = wsci * S1;
            float B = fmaf(wsci, S0, b2i);
            if (blockIdx.x == 0) STg[128*H_ + i] = make_float2(A, B);
            pm += A*h.y + B*h.x;
            pe += A*A*h.z + 2.f*A*B*h.y + B*B*h.x;
        }
        float2* red2 = (float2*)(scratch + 1024); // lb dead after merge
        red2[tid] = make_float2(pm, pe);
        __syncthreads();
        if (tid < H_) {
            float m = 0.f, e2 = 0.f;
            #pragma unroll
            for (int c2 = 0; c2 < 4; ++c2) {
                float2 r2 = red2[c2*128 + tid];
                m += r2.x; e2 += r2.y;
            }
            int slot = blockIdx.x & 63;
            atomicAdd(&ws[OFF_PM + l*16384 + slot*256 + tid], m);
            atomicAdd(&ws[OFF_PM + l*16384 + slot*256 + 128 + tid], e2);
        }
    }
}

// 129x128: block k = bin k. BN2 fold (64-slot pm/pe read), in-bin crossings,
// rank, wf-weighted toggle scan -> U/UP/C segment tables.
__global__ __launch_bounds__(128) void k_prep2(
    const float* __restrict__ bn2g, const float* __restrict__ bn2b,
    const float* __restrict__ wf, const float* __restrict__ bf,
    float* __restrict__ ws, int l) {
    const int j = threadIdx.x, k = blockIdx.x;
    __shared__ float skey[H_], sval[H_];
    __shared__ float4 sc4[H_];
    __shared__ float red[8];
    // early issue of all independent global loads
    float2 mys = ((const float2*)(ws + OFF_S))[k*H_ + j];
    float lo = (k > 0) ? ws[OFF_TS + k - 1] : -INFINITY;
    float hi = (k < NBINS - 1) ? ws[OFF_TS + k] : INFINITY;
    float w0 = wf[l*2*H_ + j], w1 = wf[l*2*H_ + H_ + j];
    float bg = bn2g[l*H_ + j], bb2 = bn2b[l*H_ + j];
    float pmv = 0.f, pev = 0.f;
    #pragma unroll
    for (int s = 0; s < 64; ++s) {
        pmv += ws[OFF_PM + l*16384 + s*256 + j];
        pev += ws[OFF_PM + l*16384 + s*256 + 128 + j];
    }
    float mean = pmv * (1.f / BN_);
    float var = fmaxf(pev * (1.f / BN_) - mean * mean, 0.f);
    float R = bg * rsqrtf(var + 1e-5f);
    float a = mys.x * R;
    float c = (mys.y - mean) * R + bb2;
    bool actv = (k == 0) ? ((a < 0.f) || (a == 0.f && c > 0.f))
                         : (fmaf(a, lo, c) > 0.f);
    float u = (a != 0.f) ? (-c / a) : INFINITY;
    bool rel = (a != 0.f) && (u > lo) && (u < hi);
    float key = rel ? u : INFINITY;
    skey[j] = key;
    __syncthreads();
    int rk = 0;
    for (int q = 0; q < H_; q++) {
        float kq = skey[q];
        rk += ((kq < key) || (kq == key && q < j)) ? 1 : 0;
    }
    float4 bb = bsum4(actv ? make_float4(w0*a, w0*c, w1*a, w1*c)
                           : make_float4(0.f, 0.f, 0.f, 0.f), red, j);
    float sg = rel ? ((a > 0.f) ? 1.f : -1.f) : 0.f;
    sval[rk] = key;
    sc4[rk] = make_float4(sg*w0*a, sg*w0*c, sg*w1*a, sg*w1*c);
    __syncthreads();
    for (int off = 1; off < H_; off <<= 1) {
        float4 add = (j >= off) ? sc4[j - off] : make_float4(0.f, 0.f, 0.f, 0.f);
        __syncthreads();
        sc4[j].x += add.x; sc4[j].y += add.y; sc4[j].z += add.z; sc4[j].w += add.w;
        __syncthreads();
    }
    float bfx = bf[2*l], bfy = bf[2*l + 1];
    ws[OFF_U + k*H_ + j] = sval[j];
    if (j < 8) ws[OFF_UP + k*8 + j] = sval[16*j + 15];
    float4* Cg = (float4*)(ws + OFF_C) + k * 132;
    float4 sj = sc4[j];
    Cg[j + 1] = make_float4(bb.x + sj.x, bb.y + bfx + sj.y,
                            bb.z + sj.z, bb.w + bfy + sj.w);
    if (j == 0) Cg[0] = make_float4(bb.x, bb.y + bfx, bb.z, bb.w + bfy);
}

// 256x1024: per-sample 2-round search + segment eval + coupling update,
// fused next-layer xin stats (64-slotted). (x0,x1,sldj) packed float4.
__global__ __launch_bounds__(1024) void k_step(
    const float* __restrict__ x,
    float* __restrict__ ws, float* __restrict__ out,
    int l, int rev, int last) {
    __shared__ float4 lup4[NBINS * 2];
    __shared__ float rsc[32];
    const int tid = threadIdx.x;
    const int b = blockIdx.x * 1024 + tid;
    // issue slow global loads FIRST; staging + barrier hides their latency
    int kb = ((const unsigned char*)(ws + OFF_KB))[b];
    float x0v, x1v, sl;
    if (l == 0) {
        float2 xv = ((const float2*)x)[b];
        x0v = xv.x; x1v = xv.y; sl = 0.f;
    } else {
        float4 xq = ((const float4*)(ws + OFF_XQ))[b];
        x0v = xq.x; x1v = xq.y; sl = xq.z;
    }
    const float4* upg = (const float4*)(ws + OFF_UP);
    for (int e = tid; e < NBINS * 2; e += 1024) lup4[e] = upg[e];
    __syncthreads();
    float xin = rev ? x1v : x0v;
    float xo  = rev ? x0v : x1v;
    float4 p0 = lup4[kb*2], p1 = lup4[kb*2 + 1];
    int s16 = (p0.x<xin)+(p0.y<xin)+(p0.z<xin)+(p0.w<xin)
            + (p1.x<xin)+(p1.y<xin)+(p1.z<xin)+(p1.w<xin);
    if (s16 > 7) s16 = 7;
    const float4* Ur = (const float4*)(ws + OFF_U + kb*H_ + s16*16);
    float4 q0 = Ur[0], q1 = Ur[1], q2 = Ur[2], q3 = Ur[3];
    int c2 = (q0.x<xin)+(q0.y<xin)+(q0.z<xin)+(q0.w<xin)
           + (q1.x<xin)+(q1.y<xin)+(q1.z<xin)+(q1.w<xin)
           + (q2.x<xin)+(q2.y<xin)+(q2.z<xin)+(q2.w<xin)
           + (q3.x<xin)+(q3.y<xin)+(q3.z<xin)+(q3.w<xin);
    int s = s16 * 16 + c2;
    float4 C = ((const float4*)(ws + OFF_C))[kb*132 + s];
    float stx = fmaf(C.x, xin, C.y);
    float sty = fmaf(C.z, xin, C.w);
    float sv = tanhf(stx);
    float y = expf(sv) * xo + sty;
    sl += sv;
    if (!last) {
        float nx0 = rev ? y : x0v;
        float nx1 = rev ? x1v : y;
        ((float4*)(ws + OFF_XQ))[b] = make_float4(nx0, nx1, sl, 0.f);
        float s1 = y, s2 = y * y;
        for (int off = 32; off; off >>= 1) {
            s1 += __shfl_down(s1, off); s2 += __shfl_down(s2, off);
        }
        int lane = tid & 63, wid = tid >> 6;
        if (lane == 0) { rsc[wid] = s1; rsc[16 + wid] = s2; }
        __syncthreads();
        if (tid == 0) {
            float aa = 0.f, cc = 0.f;
            for (int w = 0; w < 16; w++) { aa += rsc[w]; cc += rsc[16 + w]; }
            int slot = blockIdx.x & 63;
            atomicAdd(&ws[OFF_STAT + (l+1)*128 + slot*2], aa);
            atomicAdd(&ws[OFF_STAT + (l+1)*128 + slot*2 + 1], cc);
        }
    } else {
        float z0 = 1.f / (1.f + expf(-x0v));
        float z1 = 1.f / (1.f + expf(-y));
        ((float2*)out)[b] = make_float2(z0, z1);
        out[2*BN_ + b] = sl + logf(z0 * (1.f - z0) + 1e-4f)
                            + logf(z1 * (1.f - z1) + 1e-4f);
    }
}

extern "C" void kernel_launch(void* const* d_in, const int* in_sizes, int n_in,
                              void* d_out, int out_size, void* d_ws, size_t ws_size,
                              hipStream_t stream) {
    const float* x    = (const float*)d_in[0];
    const float* v1   = (const float*)d_in[1];
    const float* g1   = (const float*)d_in[2];
    // d_in[3] = b1: cancels exactly inside BN1 (affine input), unused.
    const float* bn1g = (const float*)d_in[4];
    const float* bn1b = (const float*)d_in[5];
    const float* v2   = (const float*)d_in[6];
    const float* g2   = (const float*)d_in[7];
    const float* b2   = (const float*)d_in[8];
    const float* bn2g = (const float*)d_in[9];
    const float* bn2b = (const float*)d_in[10];
    const float* wf   = (const float*)d_in[11];
    const float* bf   = (const float*)d_in[12];
    float* ws  = (float*)d_ws;
    float* out = (float*)d_out;

    hipMemsetAsync(ws, 0, 132096 * sizeof(float), stream); // stats + pm slots
    k_init<<<256, 1024, 0, stream>>>(x, v2, g2, ws);
    for (int l = 0; l < 8; l++) {
        int rev = (l % 2 == 0) ? 1 : 0;
        int last = (l == 7) ? 1 : 0;
        k_bin<<<512, 512, 0, stream>>>(x, v1, g1, bn1g, bn1b, b2, ws, l, rev);
        k_prep2<<<NBINS, 128, 0, stream>>>(bn2g, bn2b, wf, bf, ws, l);
        k_step<<<256, 1024, 0, stream>>>(x, ws, out, l, rev, last);
    }
}

// Round 16
// 298.813 us; speedup vs baseline: 1.8193x; 1.8193x over previous
//
#include <hip/hip_runtime.h>
#include <math.h>

// RealNVP, 8 layers, B=262144, H=128. Multi-kernel, 3 dispatches/layer.
// r14 structure (proven 300.9us) + 64-way atomic slotting (r15's reshape
// reverted: launch_bounds(512,4)+rT1_[32] spilled -> 137MB scratch writes).
// k_bin: 256x1024, BN1 fold + rank + binning + hist + BN2 moment fold;
//   float4-packed LDS; toggle d1 in rT1_[16]; d0 = -d1*ts.
// k_prep2: per-bin segment tables U/UP/C.
// k_step: 2-round search + 1 float4 + 2 fma + coupling; packed float4 state.

#define BN_ 262144
#define H_ 128
#define NBINS 129

// ws element offsets (4B units)
#define OFF_STAT 0                       // [l][64 slots][2] = 1024
#define OFF_PM   1024                    // [l][64 slots][256] -> 132096
#define OFF_TS   132096                  // 128 -> 132224
#define OFF_XQ   132224                  // float4 xq[BN] -> 1180800
#define OFF_KB   1180800                 // uchar[BN] -> 1246336
#define OFF_V2T  1246336                 // v2T[8][128][128] -> 1377408
#define OFF_WSC  1377408                 // [8][128] -> 1378432
#define OFF_S    1378432                 // float2 ST[129][128] -> 1411456
#define OFF_UP   1411456                 // Upiv[129][8] (16B aligned) -> 1412488
#define OFF_U    1412488                 // U[129][128] (16B aligned) -> 1429000
#define OFF_C    1429000                 // float4 C[129][132] (16B aligned)

__device__ __forceinline__ float4 bsum4(float4 v, volatile float* tmp, int tid) {
    for (int off = 32; off; off >>= 1) {
        v.x += __shfl_down(v.x, off); v.y += __shfl_down(v.y, off);
        v.z += __shfl_down(v.z, off); v.w += __shfl_down(v.w, off);
    }
    if ((tid & 63) == 0) {
        int w = (tid >> 6) * 4;
        tmp[w] = v.x; tmp[w+1] = v.y; tmp[w+2] = v.z; tmp[w+3] = v.w;
    }
    __syncthreads();
    float4 r = make_float4(tmp[0]+tmp[4], tmp[1]+tmp[5],
                           tmp[2]+tmp[6], tmp[3]+tmp[7]);
    __syncthreads();
    return r;
}

// 256x1024: stats of x1 (layer-0 xin, 64-slotted) + v2 transpose + wsc.
__global__ __launch_bounds__(1024) void k_init(const float* __restrict__ x,
    const float* __restrict__ v2, const float* __restrict__ g2,
    float* __restrict__ ws) {
    const int tid = threadIdx.x;
    __shared__ float rs[16], rss[16], w2[16];
    int b = blockIdx.x * 1024 + tid;
    float2 xv = ((const float2*)x)[b];
    float s1 = xv.y, s2 = xv.y * xv.y;
    for (int off = 32; off; off >>= 1) {
        s1 += __shfl_down(s1, off); s2 += __shfl_down(s2, off);
    }
    if ((tid & 63) == 0) { rs[tid>>6] = s1; rss[tid>>6] = s2; }
    __syncthreads();
    if (tid == 0) {
        float a = 0.f, c = 0.f;
        for (int w = 0; w < 16; w++) { a += rs[w]; c += rss[w]; }
        atomicAdd(&ws[OFF_STAT + (blockIdx.x & 63)*2], a);
        atomicAdd(&ws[OFF_STAT + (blockIdx.x & 63)*2 + 1], c);
    }
    if (blockIdx.x < 128) {
        const int l = blockIdx.x >> 4, i0 = (blockIdx.x & 15) * 8;
        const int iloc = tid >> 7, j = tid & 127;
        float val = v2[(l*H_ + i0 + iloc)*H_ + j];
        ws[OFF_V2T + (l*H_ + j)*H_ + i0 + iloc] = val;
        float s = val * val;
        for (int off = 32; off; off >>= 1) s += __shfl_down(s, off);
        if ((tid & 63) == 0) w2[tid >> 6] = s;
        __syncthreads();
        if (tid < 8)
            ws[OFF_WSC + l*H_ + i0 + tid] =
                g2[l*H_ + i0 + tid] / sqrtf(w2[2*tid] + w2[2*tid+1]);
    }
}

// 256x1024: BN1 fold + rank + binning + hist + BN2 moment fold.
__global__ __launch_bounds__(1024, 4) void k_bin(
    const float* __restrict__ x,
    const float* __restrict__ v1, const float* __restrict__ g1,
    const float* __restrict__ bn1g, const float* __restrict__ bn1b,
    const float* __restrict__ b2,
    float* __restrict__ ws, int l, int rev) {
    __shared__ float sTun[H_], sTs[H_], wscs[H_], b2s[H_];
    __shared__ float4 tcoef[H_];      // (ta, tc, ba, bc) sorted order
    __shared__ int ordr[H_];
    __shared__ float4 pTB[8][H_];     // (t1, t0, b1, b0)
    __shared__ float scratch[4192];   // ph1: prank[0,1024) | ph3.5+: hist4[0,528)
                                      // ph2-3.5: lb[1024,4192) | end: red2[1024,3072)
    float* lb = scratch + 1024;
    float4* hist4 = (float4*)scratch;
    const int tid = threadIdx.x;
    const int i = tid & 127, cc = tid >> 7;
    const float* v2T = ws + OFF_V2T + l*H_*H_;
    const int b = blockIdx.x * 1024 + tid;

    float xin;                        // early issue: hides HBM latency
    if (l == 0) xin = ((const float2*)x)[b].y;
    else {
        float4 xq = ((const float4*)(ws + OFF_XQ))[b];
        xin = rev ? xq.y : xq.x;
    }

    float a = 0.f, c = 0.f, tj = 0.f;
    if (tid < H_) {                   // phase 0: BN1 fold (block-redundant)
        float Ssum = 0.f, SSq = 0.f;
        #pragma unroll
        for (int s = 0; s < 64; ++s) {
            Ssum += ws[OFF_STAT + l*128 + 2*s];
            SSq  += ws[OFF_STAT + l*128 + 2*s + 1];
        }
        float mx = Ssum * (1.f / BN_);
        float vx = fmaxf(SSq * (1.f / BN_) - mx * mx, 0.f);
        float g1v = g1[l*H_ + tid];
        float w1 = (v1[l*H_ + tid] >= 0.f) ? g1v : -g1v;
        float r = rsqrtf(vx * g1v * g1v + 1e-5f);
        a = w1 * r * bn1g[l*H_ + tid];
        c = bn1b[l*H_ + tid] - mx * a;
        tj = (a != 0.f) ? (-c / a) : 3.0e38f;
        sTun[tid] = tj;
        wscs[tid] = ws[OFF_WSC + l*H_ + tid];
        b2s[tid] = b2[l*H_ + tid];
    }
    for (int e = tid; e < 3168; e += 1024) lb[e] = 0.f;
    __syncthreads();
    {                                 // phase 1: rank + sorted packed coeffs
        int* prank = (int*)scratch;
        float tq0 = sTun[i];
        int pr = 0;
        #pragma unroll
        for (int m = 0; m < 16; ++m) {
            int q = cc*16 + m;
            float tq = sTun[q];
            pr += (tq < tq0 || (tq == tq0 && q < i)) ? 1 : 0;
        }
        prank[cc*128 + i] = pr;
        __syncthreads();
        if (tid < H_) {
            int rk = 0;
            #pragma unroll
            for (int s = 0; s < 8; ++s) rk += prank[s*128 + tid];
            ordr[rk] = tid;
            sTs[rk] = tj;
            if (blockIdx.x == 0) ws[OFF_TS + rk] = tj;
            float sg = (a > 0.f) ? 1.f : -1.f;
            bool nz = (a != 0.f);
            bool act = (a < 0.f) || (a == 0.f && c > 0.f);
            tcoef[rk] = make_float4(nz ? sg * a : 0.f, nz ? sg * c : 0.f,
                                    act ? a : 0.f,     act ? c : 0.f);
        }
    }
    __syncthreads();
    float rT1_[16];
    {                                 // phase 2+3: bin/hist + sorted fma pass
        int pos = 0;
        #pragma unroll
        for (int s = 64; s; s >>= 1) pos += (sTs[pos + s - 1] < xin) ? s : 0;
        pos += (sTs[pos] < xin) ? 1 : 0;
        ((unsigned char*)(ws + OFF_KB))[b] = (unsigned char)pos;
        float* lbr = lb + (tid & 7) * 396;   // lane slotting: <=8-way RMW
        atomicAdd(&lbr[pos], 1.f);
        atomicAdd(&lbr[132 + pos], xin);
        atomicAdd(&lbr[264 + pos], xin * xin);

        float b1 = 0.f, b0 = 0.f, t1 = 0.f, t0 = 0.f;
        #pragma unroll
        for (int m = 0; m < 16; ++m) {
            int sm = cc*16 + m;
            float4 t4 = tcoef[sm];                // 1 b128 broadcast
            float vm = v2T[ordr[sm]*H_ + i];      // 1 b32 bcast + L2
            b1 = fmaf(vm, t4.z, b1);
            b0 = fmaf(vm, t4.w, b0);
            float d1 = vm * t4.x;
            t0 = fmaf(vm, t4.y, t0);
            rT1_[m] = d1; t1 += d1;
        }
        pTB[cc][i] = make_float4(t1, t0, b1, b0); // 1 b128 write
    }
    __syncthreads();
    // phase 3.5: merge 8 sub-histogram slots -> packed hist4 (cn, sx, sxx)
    if (tid < 132) {
        float cn = 0.f, sx = 0.f, sxx = 0.f;
        #pragma unroll
        for (int c2 = 0; c2 < 8; ++c2) {
            cn  += lb[c2*396 + tid];
            sx  += lb[c2*396 + 132 + tid];
            sxx += lb[c2*396 + 264 + tid];
        }
        hist4[tid] = make_float4(cn, sx, sxx, 0.f);
    }
    __syncthreads();
    {                                 // phase 4: prefix walk (registers) + fold
        float S1 = 0.f, S0 = 0.f;
        #pragma unroll
        for (int c2 = 0; c2 < 8; ++c2) {
            float4 p = pTB[c2][i];                // 1 b128 read
            S1 += p.z; S0 += p.w;
            if (c2 < cc) { S1 += p.x; S0 += p.y; }
        }
        float wsci = wscs[i], b2i = b2s[i];
        float pm = 0.f, pe = 0.f;
        float2* STg = (float2*)(ws + OFF_S);
        #pragma unroll
        for (int r = 0; r < 16; ++r) {
            int k = 16*cc + r;
            float4 h = hist4[k];                  // 1 b128 broadcast
            float A = wsci * S1;
            float B = fmaf(wsci, S0, b2i);
            if (blockIdx.x == 0) STg[k*H_ + i] = make_float2(A, B);
            pm += A*h.y + B*h.x;
            pe += A*A*h.z + 2.f*A*B*h.y + B*B*h.x;
            float d1 = rT1_[r];
            S1 += d1;
            S0 = fmaf(-d1, sTs[k], S0);           // d0 = -d1*ts (exact algebra)
        }
        if (cc == 7) {                // bin 128 (no toggle after)
            float4 h = hist4[128];
            float A = wsci * S1;
            float B = fmaf(wsci, S0, b2i);
            if (blockIdx.x == 0) STg[128*H_ + i] = make_float2(A, B);
            pm += A*h.y + B*h.x;
            pe += A*A*h.z + 2.f*A*B*h.y + B*B*h.x;
        }
        float2* red2 = (float2*)(scratch + 1024); // lb dead after merge
        red2[tid] = make_float2(pm, pe);
        __syncthreads();
        if (tid < H_) {
            float m = 0.f, e2 = 0.f;
            #pragma unroll
            for (int c2 = 0; c2 < 8; ++c2) {
                float2 r2 = red2[c2*128 + tid];
                m += r2.x; e2 += r2.y;
            }
            int slot = blockIdx.x & 63;
            atomicAdd(&ws[OFF_PM + l*16384 + slot*256 + tid], m);
            atomicAdd(&ws[OFF_PM + l*16384 + slot*256 + 128 + tid], e2);
        }
    }
}

// 129x128: block k = bin k. BN2 fold (64-slot pm/pe read), in-bin crossings,
// rank, wf-weighted toggle scan -> U/UP/C segment tables.
__global__ __launch_bounds__(128) void k_prep2(
    const float* __restrict__ bn2g, const float* __restrict__ bn2b,
    const float* __restrict__ wf, const float* __restrict__ bf,
    float* __restrict__ ws, int l) {
    const int j = threadIdx.x, k = blockIdx.x;
    __shared__ float skey[H_], sval[H_];
    __shared__ float4 sc4[H_];
    __shared__ float red[8];
    // early issue of all independent global loads
    float2 mys = ((const float2*)(ws + OFF_S))[k*H_ + j];
    float lo = (k > 0) ? ws[OFF_TS + k - 1] : -INFINITY;
    float hi = (k < NBINS - 1) ? ws[OFF_TS + k] : INFINITY;
    float w0 = wf[l*2*H_ + j], w1 = wf[l*2*H_ + H_ + j];
    float bg = bn2g[l*H_ + j], bb2 = bn2b[l*H_ + j];
    float pmv = 0.f, pev = 0.f;
    #pragma unroll
    for (int s = 0; s < 64; ++s) {
        pmv += ws[OFF_PM + l*16384 + s*256 + j];
        pev += ws[OFF_PM + l*16384 + s*256 + 128 + j];
    }
    float mean = pmv * (1.f / BN_);
    float var = fmaxf(pev * (1.f / BN_) - mean * mean, 0.f);
    float R = bg * rsqrtf(var + 1e-5f);
    float a = mys.x * R;
    float c = (mys.y - mean) * R + bb2;
    bool actv = (k == 0) ? ((a < 0.f) || (a == 0.f && c > 0.f))
                         : (fmaf(a, lo, c) > 0.f);
    float u = (a != 0.f) ? (-c / a) : INFINITY;
    bool rel = (a != 0.f) && (u > lo) && (u < hi);
    float key = rel ? u : INFINITY;
    skey[j] = key;
    __syncthreads();
    int rk = 0;
    for (int q = 0; q < H_; q++) {
        float kq = skey[q];
        rk += ((kq < key) || (kq == key && q < j)) ? 1 : 0;
    }
    float4 bb = bsum4(actv ? make_float4(w0*a, w0*c, w1*a, w1*c)
                           : make_float4(0.f, 0.f, 0.f, 0.f), red, j);
    float sg = rel ? ((a > 0.f) ? 1.f : -1.f) : 0.f;
    sval[rk] = key;
    sc4[rk] = make_float4(sg*w0*a, sg*w0*c, sg*w1*a, sg*w1*c);
    __syncthreads();
    for (int off = 1; off < H_; off <<= 1) {
        float4 add = (j >= off) ? sc4[j - off] : make_float4(0.f, 0.f, 0.f, 0.f);
        __syncthreads();
        sc4[j].x += add.x; sc4[j].y += add.y; sc4[j].z += add.z; sc4[j].w += add.w;
        __syncthreads();
    }
    float bfx = bf[2*l], bfy = bf[2*l + 1];
    ws[OFF_U + k*H_ + j] = sval[j];
    if (j < 8) ws[OFF_UP + k*8 + j] = sval[16*j + 15];
    float4* Cg = (float4*)(ws + OFF_C) + k * 132;
    float4 sj = sc4[j];
    Cg[j + 1] = make_float4(bb.x + sj.x, bb.y + bfx + sj.y,
                            bb.z + sj.z, bb.w + bfy + sj.w);
    if (j == 0) Cg[0] = make_float4(bb.x, bb.y + bfx, bb.z, bb.w + bfy);
}

// 256x1024: per-sample 2-round search + segment eval + coupling update,
// fused next-layer xin stats (64-slotted). (x0,x1,sldj) packed float4.
__global__ __launch_bounds__(1024) void k_step(
    const float* __restrict__ x,
    float* __restrict__ ws, float* __restrict__ out,
    int l, int rev, int last) {
    __shared__ float4 lup4[NBINS * 2];
    __shared__ float rsc[32];
    const int tid = threadIdx.x;
    const int b = blockIdx.x * 1024 + tid;
    // issue slow global loads FIRST; staging + barrier hides their latency
    int kb = ((const unsigned char*)(ws + OFF_KB))[b];
    float x0v, x1v, sl;
    if (l == 0) {
        float2 xv = ((const float2*)x)[b];
        x0v = xv.x; x1v = xv.y; sl = 0.f;
    } else {
        float4 xq = ((const float4*)(ws + OFF_XQ))[b];
        x0v = xq.x; x1v = xq.y; sl = xq.z;
    }
    const float4* upg = (const float4*)(ws + OFF_UP);
    for (int e = tid; e < NBINS * 2; e += 1024) lup4[e] = upg[e];
    __syncthreads();
    float xin = rev ? x1v : x0v;
    float xo  = rev ? x0v : x1v;
    float4 p0 = lup4[kb*2], p1 = lup4[kb*2 + 1];
    int s16 = (p0.x<xin)+(p0.y<xin)+(p0.z<xin)+(p0.w<xin)
            + (p1.x<xin)+(p1.y<xin)+(p1.z<xin)+(p1.w<xin);
    if (s16 > 7) s16 = 7;
    const float4* Ur = (const float4*)(ws + OFF_U + kb*H_ + s16*16);
    float4 q0 = Ur[0], q1 = Ur[1], q2 = Ur[2], q3 = Ur[3];
    int c2 = (q0.x<xin)+(q0.y<xin)+(q0.z<xin)+(q0.w<xin)
           + (q1.x<xin)+(q1.y<xin)+(q1.z<xin)+(q1.w<xin)
           + (q2.x<xin)+(q2.y<xin)+(q2.z<xin)+(q2.w<xin)
           + (q3.x<xin)+(q3.y<xin)+(q3.z<xin)+(q3.w<xin);
    int s = s16 * 16 + c2;
    float4 C = ((const float4*)(ws + OFF_C))[kb*132 + s];
    float stx = fmaf(C.x, xin, C.y);
    float sty = fmaf(C.z, xin, C.w);
    float sv = tanhf(stx);
    float y = expf(sv) * xo + sty;
    sl += sv;
    if (!last) {
        float nx0 = rev ? y : x0v;
        float nx1 = rev ? x1v : y;
        ((float4*)(ws + OFF_XQ))[b] = make_float4(nx0, nx1, sl, 0.f);
        float s1 = y, s2 = y * y;
        for (int off = 32; off; off >>= 1) {
            s1 += __shfl_down(s1, off); s2 += __shfl_down(s2, off);
        }
        int lane = tid & 63, wid = tid >> 6;
        if (lane == 0) { rsc[wid] = s1; rsc[16 + wid] = s2; }
        __syncthreads();
        if (tid == 0) {
            float aa = 0.f, cc = 0.f;
            for (int w = 0; w < 16; w++) { aa += rsc[w]; cc += rsc[16 + w]; }
            int slot = blockIdx.x & 63;
            atomicAdd(&ws[OFF_STAT + (l+1)*128 + slot*2], aa);
            atomicAdd(&ws[OFF_STAT + (l+1)*128 + slot*2 + 1], cc);
        }
    } else {
        float z0 = 1.f / (1.f + expf(-x0v));
        float z1 = 1.f / (1.f + expf(-y));
        ((float2*)out)[b] = make_float2(z0, z1);
        out[2*BN_ + b] = sl + logf(z0 * (1.f - z0) + 1e-4f)
                            + logf(z1 * (1.f - z1) + 1e-4f);
    }
}

extern "C" void kernel_launch(void* const* d_in, const int* in_sizes, int n_in,
                              void* d_out, int out_size, void* d_ws, size_t ws_size,
                              hipStream_t stream) {
    const float* x    = (const float*)d_in[0];
    const float* v1   = (const float*)d_in[1];
    const float* g1   = (const float*)d_in[2];
    // d_in[3] = b1: cancels exactly inside BN1 (affine input), unused.
    const float* bn1g = (const float*)d_in[4];
    const float* bn1b = (const float*)d_in[5];
    const float* v2   = (const float*)d_in[6];
    const float* g2   = (const float*)d_in[7];
    const float* b2   = (const float*)d_in[8];
    const float* bn2g = (const float*)d_in[9];
    const float* bn2b = (const float*)d_in[10];
    const float* wf   = (const float*)d_in[11];
    const float* bf   = (const float*)d_in[12];
    float* ws  = (float*)d_ws;
    float* out = (float*)d_out;

    hipMemsetAsync(ws, 0, 132096 * sizeof(float), stream); // stats + pm slots
    k_init<<<256, 1024, 0, stream>>>(x, v2, g2, ws);
    for (int l = 0; l < 8; l++) {
        int rev = (l % 2 == 0) ? 1 : 0;
        int last = (l == 7) ? 1 : 0;
        k_bin<<<256, 1024, 0, stream>>>(x, v1, g1, bn1g, bn1b, b2, ws, l, rev);
        k_prep2<<<NBINS, 128, 0, stream>>>(bn2g, bn2b, wf, bf, ws, l);
        k_step<<<256, 1024, 0, stream>>>(x, ws, out, l, rev, last);
    }
}